// Round 2
// baseline (3158.415 us; speedup 1.0000x reference)
//
#include <hip/hip_runtime.h>

// x[B][C][H][W] fp32, weight[C][1][H][1], bias[C]
// out[b,c,h,w] = sum_k weight[c,k] * x[b,c,(h+k)%H,w] + bias[c]
#define NB 32
#define NC 384
#define NH 56
#define NW 56

// One wave per (b,c) plane. Lane = w (lanes 56..63 idle).
// Weights are wave-uniform -> forced scalar (SGPR) via readfirstlane.
// Scatter form: stream x[j] once, update 56 register accumulators:
//   acc[(j-k)%56] += s_wt[k] * x[j]
// All acc indices compile-time (fully unrolled) -> stays in VGPRs.
__global__ __launch_bounds__(256, 2) void gcc_Conv2d_64347200028713_kernel(
    const float* __restrict__ x,
    const float* __restrict__ wgt,
    const float* __restrict__ bias,
    float* __restrict__ out)
{
    const int wave = threadIdx.x >> 6;
    const int lane = threadIdx.x & 63;
    const int plane = blockIdx.x * 4 + wave;        // b*NC + c
    // Force wave-uniform channel so weight/bias loads scalarize to s_load.
    const int cs = __builtin_amdgcn_readfirstlane(plane % NC);

    const float* __restrict__ wrow = wgt + cs * NH;
    float swt[NH];
#pragma unroll
    for (int k = 0; k < NH; ++k) swt[k] = wrow[k];  // uniform addr -> SGPRs
    const float bc = bias[cs];

    const float* __restrict__ xp = x   + (size_t)plane * (NH * NW);
    float* __restrict__       op = out + (size_t)plane * (NH * NW);

    const int l = (lane < NW) ? lane : 0;           // clamp idle lanes (loads safe)

    float acc[NH];
#pragma unroll
    for (int h = 0; h < NH; ++h) acc[h] = 0.f;

#pragma unroll
    for (int j = 0; j < NH; ++j) {
        const float xj = xp[j * NW + l];
#pragma unroll
        for (int k = 0; k < NH; ++k) {
            const int h = (j - k + NH) % NH;        // compile-time
            acc[h] += swt[k] * xj;
        }
    }

    if (lane < NW) {
#pragma unroll
        for (int h = 0; h < NH; ++h) op[h * NW + lane] = acc[h] + bc;
    }
}

extern "C" void kernel_launch(void* const* d_in, const int* in_sizes, int n_in,
                              void* d_out, int out_size, void* d_ws, size_t ws_size,
                              hipStream_t stream)
{
    const float* x    = (const float*)d_in[0];
    const float* wgt  = (const float*)d_in[1];
    const float* bias = (const float*)d_in[2];
    float* out        = (float*)d_out;

    const int planes = NB * NC;                     // 12288
    const int block  = 256;                         // 4 waves = 4 planes/block
    const int grid   = planes / 4;                  // 3072

    gcc_Conv2d_64347200028713_kernel<<<grid, block, 0, stream>>>(x, wgt, bias, out);
}

// Round 4
// 293.243 us; speedup vs baseline: 10.7706x; 10.7706x over previous
//
#include <hip/hip_runtime.h>

// x[B][C][H][W] fp32, weight[C][1][H][1], bias[C]
// out[b,c,h,w] = sum_k weight[c,k] * x[b,c,(h+k)%H,w] + bias[c]
#define NB 32
#define NC 384
#define NH 56
#define NW 56
#define HT 14   // h-rows per wave (4 waves cover 56)

// Block = one (b,c) plane (blockIdx.x in [0, B*C)).
// Wave t computes output rows [14t, 14t+14); lane = w (56 of 64 active).
// Weights: uniform (blockIdx-derived c) -> SGPRs, forced via readfirstlane.
// x column pre-rotated by h0 into xv[56] VGPRs (compile-time indices only).
// Inner nest: 56 x 14 = 784 FMAs (within full-unroll budget; R1's 3136 was not).
__global__ __launch_bounds__(256, 4) void gcc_Conv2d_64347200028713_kernel(
    const float* __restrict__ x,
    const float* __restrict__ wgt,
    const float* __restrict__ bias,
    float* __restrict__ out)
{
    const int plane = blockIdx.x;            // b*NC + c
    const int c     = plane % NC;            // scalar (blockIdx-derived)
    const int wave  = threadIdx.x >> 6;
    const int lane  = threadIdx.x & 63;
    const int h0    = wave * HT;
    const int l     = (lane < NW) ? lane : 0;   // clamp idle lanes

    // Per-channel weights into SGPRs (uniform address; readfirstlane forces
    // the value into the scalar file so FMAs are v_fmac v, s, v).
    const float* __restrict__ wrow = wgt + c * NH;
    float swt[NH];
#pragma unroll
    for (int k = 0; k < NH; ++k)
        swt[k] = __uint_as_float(__builtin_amdgcn_readfirstlane(__float_as_uint(wrow[k])));
    const float bc = __uint_as_float(__builtin_amdgcn_readfirstlane(__float_as_uint(bias[c])));

    const float* __restrict__ xp = x   + (size_t)plane * (NH * NW);
    float*       __restrict__ op = out + (size_t)plane * (NH * NW);

    // Load the H-column rotated by h0: xv[m] = x[(h0+m)%56][w].
    float xv[NH];
#pragma unroll
    for (int m = 0; m < NH; ++m) {
        int row = h0 + m; if (row >= NH) row -= NH;
        xv[m] = xp[row * NW + l];
    }

    float acc[HT];
#pragma unroll
    for (int h = 0; h < HT; ++h) acc[h] = 0.f;

    // out[h0+h] = sum_k swt[k] * x[(h0+h+k)%56] = sum_k swt[k] * xv[(h+k)%56]
#pragma unroll
    for (int k = 0; k < NH; ++k) {
#pragma unroll
        for (int h = 0; h < HT; ++h) {
            int m = h + k; if (m >= NH) m -= NH;   // compile-time constant
            acc[h] += swt[k] * xv[m];
        }
    }

    if (lane < NW) {
#pragma unroll
        for (int h = 0; h < HT; ++h)
            op[(h0 + h) * NW + lane] = acc[h] + bc;
    }
}

extern "C" void kernel_launch(void* const* d_in, const int* in_sizes, int n_in,
                              void* d_out, int out_size, void* d_ws, size_t ws_size,
                              hipStream_t stream)
{
    const float* x    = (const float*)d_in[0];
    const float* wgt  = (const float*)d_in[1];
    const float* bias = (const float*)d_in[2];
    float* out        = (float*)d_out;

    const int grid  = NB * NC;   // 12288 blocks, one plane each
    const int block = 256;       // 4 waves

    gcc_Conv2d_64347200028713_kernel<<<grid, block, 0, stream>>>(x, wgt, bias, out);
}